// Round 5
// baseline (514.891 us; speedup 1.0000x reference)
//
#include <hip/hip_runtime.h>
#include <hip/hip_bf16.h>

typedef __bf16 bf16;
typedef __bf16 bf16x8 __attribute__((ext_vector_type(8)));
typedef __bf16 bf16x4v __attribute__((ext_vector_type(4)));
typedef float f32x4 __attribute__((ext_vector_type(4)));

#define D_MODEL 512
#define T_SEQ   4096
#define NH      8
#define DH      64
#define M_ROWS  8192   // B*T
#define QK_SCALE 0.18033688011112042f   // 0.125 * log2(e), folded into Q

// ---------------- kernel 0: dtype detector ----------------------------------
__global__ __launch_bounds__(64) void detect_dtype(const unsigned short* __restrict__ xr,
                                                   int* __restrict__ flag)
{
  int lane = threadIdx.x;
  int cnt = 0;
  for (int i = lane; i < 4096; i += 64) {
    unsigned short u = xr[i];
    int e = (u >> 7) & 0xFF;
    bool insane = (e >= 133) || (e > 0 && e <= 96) || (e == 0 && (u & 0x7F) != 0);
    cnt += insane ? 1 : 0;
  }
#pragma unroll
  for (int off = 32; off >= 1; off >>= 1) cnt += __shfl_xor(cnt, off);
  if (lane == 0) *flag = (cnt > 400) ? 1 : 0;   // 1 = inputs are fp32
}

// ---------------- kernel 0b: convert x to bf16 -------------------------------
__global__ __launch_bounds__(256) void convert_x(const void* __restrict__ xr,
                                                 const int* __restrict__ flag,
                                                 bf16* __restrict__ xb, int n)
{
  int i = (blockIdx.x * blockDim.x + threadIdx.x) * 4;
  if (i >= n) return;
  if (*flag) {
    float4 v = *(const float4*)((const float*)xr + i);
    __align__(8) bf16 o[4] = {(bf16)v.x, (bf16)v.y, (bf16)v.z, (bf16)v.w};
    *(uint2*)(xb + i) = *(uint2*)o;
  } else {
    *(uint2*)(xb + i) = *(const uint2*)((const bf16*)xr + i);
  }
}

// ---------------- kernel 0c: biases -> fp32 ----------------------------------
__global__ __launch_bounds__(256) void convert_bias(
    const void* b0, const void* b1, const void* b2, const void* b3,
    const int* __restrict__ flag, float* __restrict__ bf)
{
  const void* ps[4] = {b0, b1, b2, b3};
  int fl = *flag;
  for (int t = threadIdx.x; t < 4 * D_MODEL; t += 256) {
    int w = t >> 9, o = t & 511;
    bf[t] = fl ? ((const float*)ps[w])[o] : (float)((const bf16*)ps[w])[o];
  }
}

// ---------------- kernel 1: per-output-channel weight quant-dequant ----------
__global__ __launch_bounds__(256) void qdq_weights(
    const void* __restrict__ Wq, const void* __restrict__ Wk,
    const void* __restrict__ Wv, const void* __restrict__ Wo,
    const int* __restrict__ flag, bf16* __restrict__ out)
{
  int wave = threadIdx.x >> 6, lane = threadIdx.x & 63;
  int gid = blockIdx.x * 4 + wave;
  int w = gid >> 9, row = gid & 511;
  const void* W = (w == 0) ? Wq : (w == 1) ? Wk : (w == 2) ? Wv : Wo;
  int fl = *flag;
  float v[8]; float amax = 0.f;
#pragma unroll
  for (int i = 0; i < 8; i++) {
    int idx = row * D_MODEL + lane + 64 * i;
    v[i] = fl ? ((const float*)W)[idx] : (float)((const bf16*)W)[idx];
    amax = fmaxf(amax, fabsf(v[i]));
  }
#pragma unroll
  for (int off = 32; off >= 1; off >>= 1) amax = fmaxf(amax, __shfl_xor(amax, off));
  float s = fmaxf(amax / 127.0f, 1e-8f);
  bf16* dst = out + (size_t)gid * D_MODEL;
#pragma unroll
  for (int i = 0; i < 8; i++) {
    float q = rintf(v[i] / s);
    q = fminf(fmaxf(q, -127.f), 127.f);
    dst[lane + 64*i] = (bf16)(q * s);
  }
}

// ---------------- kernel 2a: fused QKV GEMM (reg-prefetch pipeline) ----------
#define LDS_STRIDE 40
__global__ __launch_bounds__(256) void gemm_qkv(
    const bf16* __restrict__ A, const bf16* __restrict__ W,
    const float* __restrict__ bias,
    bf16* __restrict__ Qm, bf16* __restrict__ Km, bf16* __restrict__ VT)
{
  __shared__ __align__(16) bf16 As[128 * LDS_STRIDE];
  __shared__ __align__(16) bf16 Bs[128 * LDS_STRIDE];

  const int tid = threadIdx.x;
  const int wave = tid >> 6, lane = tid & 63;
  const int lr = lane & 15, quad = lane >> 4;
  const int wm = (wave >> 1) * 64, wn = (wave & 1) * 64;
  const int m0 = blockIdx.x * 128, n0 = blockIdx.y * 128;
  const int sec = blockIdx.y >> 2;   // 0=Q 1=K 2=V

  f32x4 acc[4][4];
#pragma unroll
  for (int i = 0; i < 4; i++)
#pragma unroll
    for (int j = 0; j < 4; j++) acc[i][j] = f32x4{0.f, 0.f, 0.f, 0.f};

  const int srow = tid >> 2;
  const int sseg = (tid & 3) * 8;

  uint4 pa[2], pb[2];
#pragma unroll
  for (int i = 0; i < 2; i++) {
    pa[i] = *(const uint4*)(A + (size_t)(m0 + srow + i*64) * D_MODEL + sseg);
    pb[i] = *(const uint4*)(W + (size_t)(n0 + srow + i*64) * D_MODEL + sseg);
  }

  for (int k0 = 0; k0 < D_MODEL; k0 += 32) {
#pragma unroll
    for (int i = 0; i < 2; i++) {
      *(uint4*)&As[(srow + i*64) * LDS_STRIDE + sseg] = pa[i];
      *(uint4*)&Bs[(srow + i*64) * LDS_STRIDE + sseg] = pb[i];
    }
    __syncthreads();
    if (k0 + 32 < D_MODEL) {
#pragma unroll
      for (int i = 0; i < 2; i++) {
        pa[i] = *(const uint4*)(A + (size_t)(m0 + srow + i*64) * D_MODEL + k0 + 32 + sseg);
        pb[i] = *(const uint4*)(W + (size_t)(n0 + srow + i*64) * D_MODEL + k0 + 32 + sseg);
      }
    }
    bf16x8 af[4], bfr[4];
#pragma unroll
    for (int mt = 0; mt < 4; mt++) af[mt]  = *(bf16x8*)&As[(wm + mt*16 + lr) * LDS_STRIDE + quad*8];
#pragma unroll
    for (int nt = 0; nt < 4; nt++) bfr[nt] = *(bf16x8*)&Bs[(wn + nt*16 + lr) * LDS_STRIDE + quad*8];
#pragma unroll
    for (int mt = 0; mt < 4; mt++)
#pragma unroll
      for (int nt = 0; nt < 4; nt++)
        acc[mt][nt] = __builtin_amdgcn_mfma_f32_16x16x32_bf16(af[mt], bfr[nt], acc[mt][nt], 0, 0, 0);
    __syncthreads();
  }

  const float scale = (sec == 0) ? QK_SCALE : 1.0f;
#pragma unroll
  for (int mt = 0; mt < 4; mt++) {
    int grow = m0 + wm + mt * 16 + quad * 4;
#pragma unroll
    for (int nt = 0; nt < 4; nt++) {
      int gcol = n0 + wn + nt * 16 + lr;
      float b = bias[gcol];
      if (sec == 2) {               // VT[ch][token], packed x4
        bf16x4v pk;
#pragma unroll
        for (int r = 0; r < 4; r++) pk[r] = (bf16)(acc[mt][nt][r] + b);
        *(bf16x4v*)(VT + (size_t)(gcol - 1024) * M_ROWS + grow) = pk;
      } else {
        bf16* dst = (sec == 0) ? Qm : Km;
        int c = gcol & 511;
#pragma unroll
        for (int r = 0; r < 4; r++)
          dst[(size_t)(grow + r) * D_MODEL + c] = (bf16)((acc[mt][nt][r] + b) * scale);
      }
    }
  }
}

// ---------------- kernel 2b: O-proj GEMM, 64x128, fp32 out + absmax ----------
__global__ __launch_bounds__(256) void gemm_o(
    const bf16* __restrict__ A, const bf16* __restrict__ W,
    const float* __restrict__ bias,
    float* __restrict__ Cf, unsigned int* __restrict__ amaxp)
{
  __shared__ __align__(16) bf16 As[64 * LDS_STRIDE];
  __shared__ __align__(16) bf16 Bs[128 * LDS_STRIDE];
  __shared__ float wred[4];

  const int tid = threadIdx.x;
  const int wave = tid >> 6, lane = tid & 63;
  const int lr = lane & 15, quad = lane >> 4;
  const int wm = (wave >> 1) * 32, wn = (wave & 1) * 64;
  const int m0 = blockIdx.x * 64, n0 = blockIdx.y * 128;

  f32x4 acc[2][4];
#pragma unroll
  for (int i = 0; i < 2; i++)
#pragma unroll
    for (int j = 0; j < 4; j++) acc[i][j] = f32x4{0.f, 0.f, 0.f, 0.f};

  const int srow = tid >> 2;
  const int sseg = (tid & 3) * 8;

  uint4 pa, pb[2];
  pa = *(const uint4*)(A + (size_t)(m0 + srow) * D_MODEL + sseg);
#pragma unroll
  for (int i = 0; i < 2; i++)
    pb[i] = *(const uint4*)(W + (size_t)(n0 + srow + i*64) * D_MODEL + sseg);

  for (int k0 = 0; k0 < D_MODEL; k0 += 32) {
    *(uint4*)&As[srow * LDS_STRIDE + sseg] = pa;
#pragma unroll
    for (int i = 0; i < 2; i++)
      *(uint4*)&Bs[(srow + i*64) * LDS_STRIDE + sseg] = pb[i];
    __syncthreads();
    if (k0 + 32 < D_MODEL) {
      pa = *(const uint4*)(A + (size_t)(m0 + srow) * D_MODEL + k0 + 32 + sseg);
#pragma unroll
      for (int i = 0; i < 2; i++)
        pb[i] = *(const uint4*)(W + (size_t)(n0 + srow + i*64) * D_MODEL + k0 + 32 + sseg);
    }
    bf16x8 af[2], bfr[4];
#pragma unroll
    for (int mt = 0; mt < 2; mt++) af[mt]  = *(bf16x8*)&As[(wm + mt*16 + lr) * LDS_STRIDE + quad*8];
#pragma unroll
    for (int nt = 0; nt < 4; nt++) bfr[nt] = *(bf16x8*)&Bs[(wn + nt*16 + lr) * LDS_STRIDE + quad*8];
#pragma unroll
    for (int mt = 0; mt < 2; mt++)
#pragma unroll
      for (int nt = 0; nt < 4; nt++)
        acc[mt][nt] = __builtin_amdgcn_mfma_f32_16x16x32_bf16(af[mt], bfr[nt], acc[mt][nt], 0, 0, 0);
    __syncthreads();
  }

  float lmax = 0.f;
#pragma unroll
  for (int mt = 0; mt < 2; mt++) {
    int grow = m0 + wm + mt * 16 + quad * 4;
#pragma unroll
    for (int nt = 0; nt < 4; nt++) {
      int gcol = n0 + wn + nt * 16 + lr;
      float b = bias[gcol];
#pragma unroll
      for (int r = 0; r < 4; r++) {
        float v = acc[mt][nt][r] + b;
        Cf[(size_t)(grow + r) * D_MODEL + gcol] = v;
        lmax = fmaxf(lmax, fabsf(v));
      }
    }
  }
#pragma unroll
  for (int off = 32; off >= 1; off >>= 1) lmax = fmaxf(lmax, __shfl_xor(lmax, off));
  if (lane == 0) wred[wave] = lmax;
  __syncthreads();
  if (tid == 0) {
    float m = fmaxf(fmaxf(wred[0], wred[1]), fmaxf(wred[2], wred[3]));
    atomicMax(amaxp, __float_as_uint(m));
  }
}

// ---------------- kernel 3: flash attention, S^T, 2-wave blocks --------------
// grid (T/64, B*H), 128 thr = 2 waves; wave = 32 q (2 sub-tiles); 64-key chunks.
// 1024 blocks -> 4 blocks/CU. Reg-prefetch of next K/V chunk hides global lat.
#define KV_STRIDE 72
__global__ __launch_bounds__(128, 2) void attn(
    const bf16* __restrict__ Q, const bf16* __restrict__ K, const bf16* __restrict__ VT,
    const int* __restrict__ mask, bf16* __restrict__ ctx)
{
  __shared__ __align__(16) bf16 Ks [64 * KV_STRIDE];
  __shared__ __align__(16) bf16 VTs[64 * KV_STRIDE];
  __shared__ __align__(16) bf16 Pb [2][32 * KV_STRIDE];
  __shared__ __align__(16) float Msk[64];

  const int tid = threadIdx.x, wave = tid >> 6, lane = tid & 63;
  const int lr = lane & 15, quad = lane >> 4;
  const int bh = blockIdx.y; const int b = bh >> 3, h = bh & 7;
  const int qbase = blockIdx.x * 64 + wave * 32;

  bf16x8 qf[2][2];
#pragma unroll
  for (int s = 0; s < 2; s++) {
    const size_t rowQ = (size_t)(b * T_SEQ + qbase + s*16 + lr) * D_MODEL + h * DH;
    qf[s][0] = *(const bf16x8*)(Q + rowQ + quad * 8);
    qf[s][1] = *(const bf16x8*)(Q + rowQ + 32 + quad * 8);
  }

  f32x4 O[2][4];
#pragma unroll
  for (int s = 0; s < 2; s++)
#pragma unroll
    for (int i = 0; i < 4; i++) O[s][i] = f32x4{0.f, 0.f, 0.f, 0.f};
  float mrow[2] = {-1e30f, -1e30f}, lrow[2] = {0.f, 0.f};

  const int srow = tid >> 1;          // 0..63
  const int sseg = (tid & 1) * 32;    // 0 / 32
  const int* maskb = mask + b * T_SEQ;
  const bf16* baseK = K  + (size_t)(b * T_SEQ + srow) * D_MODEL + h * DH + sseg;
  const bf16* baseV = VT + (size_t)(h * DH + srow) * M_ROWS + b * T_SEQ + sseg;

  uint4 kreg[4], vreg[4]; int mreg = 0;
#pragma unroll
  for (int j = 0; j < 4; j++) {
    kreg[j] = *(const uint4*)(baseK + j*8);
    vreg[j] = *(const uint4*)(baseV + j*8);
  }
  if (tid < 64) mreg = maskb[tid];

  for (int kb = 0; kb < T_SEQ; kb += 64) {
#pragma unroll
    for (int j = 0; j < 4; j++) {
      *(uint4*)&Ks [srow * KV_STRIDE + sseg + j*8] = kreg[j];
      *(uint4*)&VTs[srow * KV_STRIDE + sseg + j*8] = vreg[j];
    }
    if (tid < 64) Msk[tid] = mreg ? 0.f : -1e30f;
    __syncthreads();
    if (kb + 64 < T_SEQ) {
#pragma unroll
      for (int j = 0; j < 4; j++) {
        kreg[j] = *(const uint4*)(baseK + (size_t)(kb + 64) * D_MODEL + j*8);
        vreg[j] = *(const uint4*)(baseV + kb + 64 + j*8);
      }
      if (tid < 64) mreg = maskb[kb + 64 + tid];
    }

    // S^T[key=16mt+4quad+r][q], mask folded into MFMA C-init
    f32x4 S[2][4];
#pragma unroll
    for (int mt = 0; mt < 4; mt++) {
      bf16x8 kf0 = *(bf16x8*)&Ks[(mt*16 + lr) * KV_STRIDE + quad*8];
      bf16x8 kf1 = *(bf16x8*)&Ks[(mt*16 + lr) * KV_STRIDE + 32 + quad*8];
      f32x4 mk = *(f32x4*)&Msk[mt*16 + quad*4];
#pragma unroll
      for (int s = 0; s < 2; s++) {
        f32x4 z = mk;
        z = __builtin_amdgcn_mfma_f32_16x16x32_bf16(kf0, qf[s][0], z, 0, 0, 0);
        z = __builtin_amdgcn_mfma_f32_16x16x32_bf16(kf1, qf[s][1], z, 0, 0, 0);
        S[s][mt] = z;
      }
    }

    float alpha[2];
#pragma unroll
    for (int s = 0; s < 2; s++) {
      float cm = -1e30f;
#pragma unroll
      for (int mt = 0; mt < 4; mt++)
#pragma unroll
        for (int r = 0; r < 4; r++) cm = fmaxf(cm, S[s][mt][r]);
      cm = fmaxf(cm, __shfl_xor(cm, 16));
      cm = fmaxf(cm, __shfl_xor(cm, 32));
      float mn = fmaxf(mrow[s], cm);
      alpha[s] = exp2f(mrow[s] - mn);
      mrow[s] = mn;
      float ls = 0.f;
#pragma unroll
      for (int mt = 0; mt < 4; mt++) {
        bf16x4v pk;
#pragma unroll
        for (int r = 0; r < 4; r++) {
          float p = exp2f(S[s][mt][r] - mn);
          ls += p;
          pk[r] = (bf16)p;
        }
        *(bf16x4v*)&Pb[wave][(s*16 + lr) * KV_STRIDE + mt*16 + quad*4] = pk;
      }
      ls += __shfl_xor(ls, 16);
      ls += __shfl_xor(ls, 32);
      lrow[s] = lrow[s] * alpha[s] + ls;
    }

    float aO[2][4];
#pragma unroll
    for (int s = 0; s < 2; s++)
#pragma unroll
      for (int r = 0; r < 4; r++) aO[s][r] = __shfl(alpha[s], quad*4 + r);

    bf16x8 pf[2][2];
#pragma unroll
    for (int s = 0; s < 2; s++) {
      pf[s][0] = *(bf16x8*)&Pb[wave][(s*16 + lr) * KV_STRIDE + quad*8];
      pf[s][1] = *(bf16x8*)&Pb[wave][(s*16 + lr) * KV_STRIDE + 32 + quad*8];
    }
#pragma unroll
    for (int nt = 0; nt < 4; nt++) {
      bf16x8 vf0 = *(bf16x8*)&VTs[(nt*16 + lr) * KV_STRIDE + quad*8];
      bf16x8 vf1 = *(bf16x8*)&VTs[(nt*16 + lr) * KV_STRIDE + 32 + quad*8];
#pragma unroll
      for (int s = 0; s < 2; s++) {
        f32x4 o = O[s][nt];
#pragma unroll
        for (int r = 0; r < 4; r++) o[r] *= aO[s][r];
        o = __builtin_amdgcn_mfma_f32_16x16x32_bf16(pf[s][0], vf0, o, 0, 0, 0);
        o = __builtin_amdgcn_mfma_f32_16x16x32_bf16(pf[s][1], vf1, o, 0, 0, 0);
        O[s][nt] = o;
      }
    }
    __syncthreads();
  }

#pragma unroll
  for (int s = 0; s < 2; s++) {
    float linv = 1.0f / lrow[s];
    float lO[4];
#pragma unroll
    for (int r = 0; r < 4; r++) lO[r] = __shfl(linv, quad*4 + r);
#pragma unroll
    for (int nt = 0; nt < 4; nt++)
#pragma unroll
      for (int r = 0; r < 4; r++) {
        size_t row = (size_t)(b * T_SEQ + qbase + s*16 + quad*4 + r);
        ctx[row * D_MODEL + h * DH + nt*16 + lr] = (bf16)(O[s][nt][r] * lO[r]);
      }
  }
}

// ---------------- kernel 4: per-tensor activation quant-dequant --------------
__global__ __launch_bounds__(256) void act_qdq(
    const float* __restrict__ pre, const unsigned int* __restrict__ amaxp,
    const int* __restrict__ flag, void* __restrict__ outv, int n)
{
  int i = (blockIdx.x * blockDim.x + threadIdx.x) * 4;
  if (i >= n) return;
  float s = fmaxf(__uint_as_float(*amaxp) / 127.0f, 1e-8f);
  float4 v = *(const float4*)(pre + i);
  float o[4] = {v.x, v.y, v.z, v.w};
#pragma unroll
  for (int r = 0; r < 4; r++) {
    float q = rintf(o[r] / s);
    q = fminf(fmaxf(q, -127.f), 127.f);
    o[r] = q * s;
  }
  if (*flag) {
    *(float4*)((float*)outv + i) = make_float4(o[0], o[1], o[2], o[3]);
  } else {
    __align__(8) bf16 ob[4] = {(bf16)o[0], (bf16)o[1], (bf16)o[2], (bf16)o[3]};
    *(uint2*)((bf16*)outv + i) = *(uint2*)ob;
  }
}

// ---------------- launch -----------------------------------------------------
extern "C" void kernel_launch(void* const* d_in, const int* in_sizes, int n_in,
                              void* d_out, int out_size, void* d_ws, size_t ws_size,
                              hipStream_t stream) {
  const void* x    = d_in[0];
  const int*  mask = (const int*)d_in[1];
  const void* Wq = d_in[2]; const void* bq = d_in[3];
  const void* Wk = d_in[4]; const void* bk = d_in[5];
  const void* Wv = d_in[6]; const void* bv = d_in[7];
  const void* Wo = d_in[8]; const void* bo = d_in[9];

  char* ws = (char*)d_ws;
  int*  flag  = (int*)(ws + 0);
  unsigned int* amax = (unsigned int*)(ws + 64);
  float* biasf = (float*)(ws + 1024);
  bf16* Wt  = (bf16*)(ws + 16384);                    // 2 MB (rows: Q,K,V,O)
  bf16* xb  = (bf16*)(ws + 4194304);                  // 8 MB
  bf16* Qm  = (bf16*)(ws + 12582912);                 // 8 MB (pre-scaled)
  bf16* Km  = (bf16*)(ws + 20971520);                 // 8 MB
  bf16* VT  = (bf16*)(ws + 29360128);                 // 8 MB: VT[ch][token]
  bf16* Cm  = (bf16*)(ws + 4194304);                  // overlays xb
  float* pre = (float*)(ws + 12582912);               // overlays Qm+Km

  hipMemsetAsync(amax, 0, 4, stream);
  detect_dtype<<<1, 64, 0, stream>>>((const unsigned short*)x, flag);
  convert_x<<<4096, 256, 0, stream>>>(x, flag, xb, M_ROWS * D_MODEL);
  convert_bias<<<1, 256, 0, stream>>>(bq, bk, bv, bo, flag, biasf);
  qdq_weights<<<512, 256, 0, stream>>>(Wq, Wk, Wv, Wo, flag, Wt);
  gemm_qkv<<<dim3(64, 12), 256, 0, stream>>>(xb, Wt, biasf, Qm, Km, VT);
  attn<<<dim3(64, 16), 128, 0, stream>>>(Qm, Km, VT, mask, Cm);
  gemm_o<<<dim3(128, 4), 256, 0, stream>>>(Cm, Wt + 3*262144, biasf + 1536, pre, amax);
  act_qdq<<<4096, 256, 0, stream>>>(pre, amax, flag, d_out, M_ROWS * D_MODEL);
}

// Round 6
// 308.191 us; speedup vs baseline: 1.6707x; 1.6707x over previous
//
#include <hip/hip_runtime.h>
#include <hip/hip_bf16.h>

typedef __bf16 bf16;
typedef __bf16 bf16x8 __attribute__((ext_vector_type(8)));
typedef __bf16 bf16x4v __attribute__((ext_vector_type(4)));
typedef float f32x4 __attribute__((ext_vector_type(4)));

#define D_MODEL 512
#define T_SEQ   4096
#define NH      8
#define DH      64
#define M_ROWS  8192   // B*T
#define QK_SCALE 0.18033688011112042f   // 0.125 * log2(e), folded into Q

// ---------------- kernel 0: dtype detector ----------------------------------
__global__ __launch_bounds__(64) void detect_dtype(const unsigned short* __restrict__ xr,
                                                   int* __restrict__ flag)
{
  int lane = threadIdx.x;
  int cnt = 0;
  for (int i = lane; i < 4096; i += 64) {
    unsigned short u = xr[i];
    int e = (u >> 7) & 0xFF;
    bool insane = (e >= 133) || (e > 0 && e <= 96) || (e == 0 && (u & 0x7F) != 0);
    cnt += insane ? 1 : 0;
  }
#pragma unroll
  for (int off = 32; off >= 1; off >>= 1) cnt += __shfl_xor(cnt, off);
  if (lane == 0) *flag = (cnt > 400) ? 1 : 0;   // 1 = inputs are fp32
}

// ---------------- kernel 0b: convert x to bf16 -------------------------------
__global__ __launch_bounds__(256) void convert_x(const void* __restrict__ xr,
                                                 const int* __restrict__ flag,
                                                 bf16* __restrict__ xb, int n)
{
  int i = (blockIdx.x * blockDim.x + threadIdx.x) * 4;
  if (i >= n) return;
  if (*flag) {
    float4 v = *(const float4*)((const float*)xr + i);
    __align__(8) bf16 o[4] = {(bf16)v.x, (bf16)v.y, (bf16)v.z, (bf16)v.w};
    *(uint2*)(xb + i) = *(uint2*)o;
  } else {
    *(uint2*)(xb + i) = *(const uint2*)((const bf16*)xr + i);
  }
}

// ---------------- kernel 0c: biases -> fp32 ----------------------------------
__global__ __launch_bounds__(256) void convert_bias(
    const void* b0, const void* b1, const void* b2, const void* b3,
    const int* __restrict__ flag, float* __restrict__ bf)
{
  const void* ps[4] = {b0, b1, b2, b3};
  int fl = *flag;
  for (int t = threadIdx.x; t < 4 * D_MODEL; t += 256) {
    int w = t >> 9, o = t & 511;
    bf[t] = fl ? ((const float*)ps[w])[o] : (float)((const bf16*)ps[w])[o];
  }
}

// ---------------- kernel 1: per-output-channel weight quant-dequant ----------
__global__ __launch_bounds__(256) void qdq_weights(
    const void* __restrict__ Wq, const void* __restrict__ Wk,
    const void* __restrict__ Wv, const void* __restrict__ Wo,
    const int* __restrict__ flag, bf16* __restrict__ out)
{
  int wave = threadIdx.x >> 6, lane = threadIdx.x & 63;
  int gid = blockIdx.x * 4 + wave;
  int w = gid >> 9, row = gid & 511;
  const void* W = (w == 0) ? Wq : (w == 1) ? Wk : (w == 2) ? Wv : Wo;
  int fl = *flag;
  float v[8]; float amax = 0.f;
#pragma unroll
  for (int i = 0; i < 8; i++) {
    int idx = row * D_MODEL + lane + 64 * i;
    v[i] = fl ? ((const float*)W)[idx] : (float)((const bf16*)W)[idx];
    amax = fmaxf(amax, fabsf(v[i]));
  }
#pragma unroll
  for (int off = 32; off >= 1; off >>= 1) amax = fmaxf(amax, __shfl_xor(amax, off));
  float s = fmaxf(amax / 127.0f, 1e-8f);
  bf16* dst = out + (size_t)gid * D_MODEL;
#pragma unroll
  for (int i = 0; i < 8; i++) {
    float q = rintf(v[i] / s);
    q = fminf(fmaxf(q, -127.f), 127.f);
    dst[lane + 64*i] = (bf16)(q * s);
  }
}

// ---------------- kernel 2a: fused QKV GEMM ----------------------------------
#define LDS_STRIDE 40
__global__ __launch_bounds__(256) void gemm_qkv(
    const bf16* __restrict__ A, const bf16* __restrict__ W,
    const float* __restrict__ bias,
    bf16* __restrict__ Qm, bf16* __restrict__ Km, bf16* __restrict__ VT)
{
  __shared__ __align__(16) bf16 As[128 * LDS_STRIDE];
  __shared__ __align__(16) bf16 Bs[128 * LDS_STRIDE];

  const int tid = threadIdx.x;
  const int wave = tid >> 6, lane = tid & 63;
  const int lr = lane & 15, quad = lane >> 4;
  const int wm = (wave >> 1) * 64, wn = (wave & 1) * 64;
  const int m0 = blockIdx.x * 128, n0 = blockIdx.y * 128;
  const int sec = blockIdx.y >> 2;   // 0=Q 1=K 2=V

  f32x4 acc[4][4];
#pragma unroll
  for (int i = 0; i < 4; i++)
#pragma unroll
    for (int j = 0; j < 4; j++) acc[i][j] = f32x4{0.f, 0.f, 0.f, 0.f};

  const int srow = tid >> 2;
  const int sseg = (tid & 3) * 8;

  for (int k0 = 0; k0 < D_MODEL; k0 += 32) {
#pragma unroll
    for (int i = 0; i < 2; i++) {
      int r = srow + i * 64;
      *(uint4*)&As[r * LDS_STRIDE + sseg] = *(const uint4*)(A + (size_t)(m0 + r) * D_MODEL + k0 + sseg);
      *(uint4*)&Bs[r * LDS_STRIDE + sseg] = *(const uint4*)(W + (size_t)(n0 + r) * D_MODEL + k0 + sseg);
    }
    __syncthreads();
    bf16x8 af[4], bfr[4];
#pragma unroll
    for (int mt = 0; mt < 4; mt++) af[mt]  = *(bf16x8*)&As[(wm + mt*16 + lr) * LDS_STRIDE + quad*8];
#pragma unroll
    for (int nt = 0; nt < 4; nt++) bfr[nt] = *(bf16x8*)&Bs[(wn + nt*16 + lr) * LDS_STRIDE + quad*8];
#pragma unroll
    for (int mt = 0; mt < 4; mt++)
#pragma unroll
      for (int nt = 0; nt < 4; nt++)
        acc[mt][nt] = __builtin_amdgcn_mfma_f32_16x16x32_bf16(af[mt], bfr[nt], acc[mt][nt], 0, 0, 0);
    __syncthreads();
  }

  const float scale = (sec == 0) ? QK_SCALE : 1.0f;
#pragma unroll
  for (int mt = 0; mt < 4; mt++) {
    int grow = m0 + wm + mt * 16 + quad * 4;
#pragma unroll
    for (int nt = 0; nt < 4; nt++) {
      int gcol = n0 + wn + nt * 16 + lr;
      float b = bias[gcol];
      if (sec == 2) {               // VT[ch][token], packed x4
        bf16x4v pk;
#pragma unroll
        for (int r = 0; r < 4; r++) pk[r] = (bf16)(acc[mt][nt][r] + b);
        *(bf16x4v*)(VT + (size_t)(gcol - 1024) * M_ROWS + grow) = pk;
      } else {
        bf16* dst = (sec == 0) ? Qm : Km;
        int c = gcol & 511;
#pragma unroll
        for (int r = 0; r < 4; r++)
          dst[(size_t)(grow + r) * D_MODEL + c] = (bf16)((acc[mt][nt][r] + b) * scale);
      }
    }
  }
}

// ---------------- kernel 2b: O-proj GEMM, 64x128, fp32 out + absmax ----------
__global__ __launch_bounds__(256) void gemm_o(
    const bf16* __restrict__ A, const bf16* __restrict__ W,
    const float* __restrict__ bias,
    float* __restrict__ Cf, unsigned int* __restrict__ amaxp)
{
  __shared__ __align__(16) bf16 As[64 * LDS_STRIDE];
  __shared__ __align__(16) bf16 Bs[128 * LDS_STRIDE];
  __shared__ float wred[4];

  const int tid = threadIdx.x;
  const int wave = tid >> 6, lane = tid & 63;
  const int lr = lane & 15, quad = lane >> 4;
  const int wm = (wave >> 1) * 32, wn = (wave & 1) * 64;
  const int m0 = blockIdx.x * 64, n0 = blockIdx.y * 128;

  f32x4 acc[2][4];
#pragma unroll
  for (int i = 0; i < 2; i++)
#pragma unroll
    for (int j = 0; j < 4; j++) acc[i][j] = f32x4{0.f, 0.f, 0.f, 0.f};

  const int srow = tid >> 2;
  const int sseg = (tid & 3) * 8;

  for (int k0 = 0; k0 < D_MODEL; k0 += 32) {
    *(uint4*)&As[srow * LDS_STRIDE + sseg] = *(const uint4*)(A + (size_t)(m0 + srow) * D_MODEL + k0 + sseg);
#pragma unroll
    for (int i = 0; i < 2; i++) {
      int r = srow + i * 64;
      *(uint4*)&Bs[r * LDS_STRIDE + sseg] = *(const uint4*)(W + (size_t)(n0 + r) * D_MODEL + k0 + sseg);
    }
    __syncthreads();
    bf16x8 af[2], bfr[4];
#pragma unroll
    for (int mt = 0; mt < 2; mt++) af[mt]  = *(bf16x8*)&As[(wm + mt*16 + lr) * LDS_STRIDE + quad*8];
#pragma unroll
    for (int nt = 0; nt < 4; nt++) bfr[nt] = *(bf16x8*)&Bs[(wn + nt*16 + lr) * LDS_STRIDE + quad*8];
#pragma unroll
    for (int mt = 0; mt < 2; mt++)
#pragma unroll
      for (int nt = 0; nt < 4; nt++)
        acc[mt][nt] = __builtin_amdgcn_mfma_f32_16x16x32_bf16(af[mt], bfr[nt], acc[mt][nt], 0, 0, 0);
    __syncthreads();
  }

  float lmax = 0.f;
#pragma unroll
  for (int mt = 0; mt < 2; mt++) {
    int grow = m0 + wm + mt * 16 + quad * 4;
#pragma unroll
    for (int nt = 0; nt < 4; nt++) {
      int gcol = n0 + wn + nt * 16 + lr;
      float b = bias[gcol];
#pragma unroll
      for (int r = 0; r < 4; r++) {
        float v = acc[mt][nt][r] + b;
        Cf[(size_t)(grow + r) * D_MODEL + gcol] = v;
        lmax = fmaxf(lmax, fabsf(v));
      }
    }
  }
#pragma unroll
  for (int off = 32; off >= 1; off >>= 1) lmax = fmaxf(lmax, __shfl_xor(lmax, off));
  if (lane == 0) wred[wave] = lmax;
  __syncthreads();
  if (tid == 0) {
    float m = fmaxf(fmaxf(wred[0], wred[1]), fmaxf(wred[2], wred[3]));
    atomicMax(amaxp, __float_as_uint(m));
  }
}

// ---------------- kernel 3: flash attention, S^T, fixed-shift softmax --------
// grid (T/64, B*H), 256 thr = 4 waves x 16 q-rows; 64-key chunks.
// No online max: scores are bounded; subtract fixed 16 via mask C-init
// (keep ? -16 : -1e30) — numerator & denominator scale identically.
// Double-buffered K/V LDS: ONE barrier per chunk; staging loads issued
// before compute so global latency overlaps MFMA/softmax.
#define KV_STRIDE 72
__global__ __launch_bounds__(256) void attn(
    const bf16* __restrict__ Q, const bf16* __restrict__ K, const bf16* __restrict__ VT,
    const int* __restrict__ mask, bf16* __restrict__ ctx)
{
  __shared__ __align__(16) bf16 Ks [2][64 * KV_STRIDE];
  __shared__ __align__(16) bf16 VTs[2][64 * KV_STRIDE];
  __shared__ __align__(16) bf16 Pb [4][16 * KV_STRIDE];
  __shared__ __align__(16) float Msk[2][64];

  const int tid = threadIdx.x, wave = tid >> 6, lane = tid & 63;
  const int lr = lane & 15, quad = lane >> 4;
  const int bh = blockIdx.y; const int b = bh >> 3, h = bh & 7;
  const int q0 = blockIdx.x * 64 + wave * 16;

  const size_t rowQ = (size_t)(b * T_SEQ + q0 + lr) * D_MODEL + h * DH;
  bf16x8 qf0 = *(const bf16x8*)(Q + rowQ + quad * 8);
  bf16x8 qf1 = *(const bf16x8*)(Q + rowQ + 32 + quad * 8);

  f32x4 O[4];
#pragma unroll
  for (int i = 0; i < 4; i++) O[i] = f32x4{0.f, 0.f, 0.f, 0.f};
  float lacc = 0.f;   // per-lane partial sum of exp2(S-16) for q=lr

  const int srow = tid >> 2;        // 0..63
  const int sseg = (tid & 3) * 16;  // 0/16/32/48
  const int* maskb = mask + b * T_SEQ;
  const bf16* baseK = K  + (size_t)(b * T_SEQ + srow) * D_MODEL + h * DH + sseg;
  const bf16* baseV = VT + (size_t)(h * DH + srow) * M_ROWS + b * T_SEQ + sseg;

  { // stage chunk 0 -> buf 0
    uint4 k0 = *(const uint4*)baseK;
    uint4 k1 = *(const uint4*)(baseK + 8);
    uint4 v0 = *(const uint4*)baseV;
    uint4 v1 = *(const uint4*)(baseV + 8);
    *(uint4*)&Ks [0][srow * KV_STRIDE + sseg]     = k0;
    *(uint4*)&Ks [0][srow * KV_STRIDE + sseg + 8] = k1;
    *(uint4*)&VTs[0][srow * KV_STRIDE + sseg]     = v0;
    *(uint4*)&VTs[0][srow * KV_STRIDE + sseg + 8] = v1;
    if (tid < 64) Msk[0][tid] = maskb[tid] ? -16.0f : -1e30f;
  }
  __syncthreads();

  for (int kb = 0; kb < T_SEQ; kb += 64) {
    const int buf = (kb >> 6) & 1;
    const bool nxt = (kb + 64) < T_SEQ;
    uint4 kr0, kr1, vr0, vr1; int mreg = 0;
    if (nxt) {   // issue next chunk's global loads now; latency hides under compute
      const bf16* nK = baseK + (size_t)(kb + 64) * D_MODEL;
      const bf16* nV = baseV + (kb + 64);
      kr0 = *(const uint4*)nK; kr1 = *(const uint4*)(nK + 8);
      vr0 = *(const uint4*)nV; vr1 = *(const uint4*)(nV + 8);
      if (tid < 64) mreg = maskb[kb + 64 + tid];
    }

    // S^T[key=16mt+4quad+r][q=lr]; mask & fixed -16 shift in C-init
    f32x4 S[4];
#pragma unroll
    for (int mt = 0; mt < 4; mt++) {
      bf16x8 kf0 = *(bf16x8*)&Ks[buf][(mt*16 + lr) * KV_STRIDE + quad*8];
      bf16x8 kf1 = *(bf16x8*)&Ks[buf][(mt*16 + lr) * KV_STRIDE + 32 + quad*8];
      f32x4 z = *(f32x4*)&Msk[buf][mt*16 + quad*4];
      z = __builtin_amdgcn_mfma_f32_16x16x32_bf16(kf0, qf0, z, 0, 0, 0);
      z = __builtin_amdgcn_mfma_f32_16x16x32_bf16(kf1, qf1, z, 0, 0, 0);
      S[mt] = z;
    }

    // exp2 + per-lane sum + P^T write (packed b64)
#pragma unroll
    for (int mt = 0; mt < 4; mt++) {
      bf16x4v pk;
#pragma unroll
      for (int r = 0; r < 4; r++) {
        float p = exp2f(S[mt][r]);
        lacc += p;
        pk[r] = (bf16)p;
      }
      *(bf16x4v*)&Pb[wave][lr * KV_STRIDE + mt*16 + quad*4] = pk;
    }

    // PV: pure accumulate, no rescale (same-wave LDS, in-order)
    bf16x8 pf0 = *(bf16x8*)&Pb[wave][lr * KV_STRIDE + quad*8];
    bf16x8 pf1 = *(bf16x8*)&Pb[wave][lr * KV_STRIDE + 32 + quad*8];
#pragma unroll
    for (int nt = 0; nt < 4; nt++) {
      bf16x8 vf0 = *(bf16x8*)&VTs[buf][(nt*16 + lr) * KV_STRIDE + quad*8];
      bf16x8 vf1 = *(bf16x8*)&VTs[buf][(nt*16 + lr) * KV_STRIDE + 32 + quad*8];
      O[nt] = __builtin_amdgcn_mfma_f32_16x16x32_bf16(pf0, vf0, O[nt], 0, 0, 0);
      O[nt] = __builtin_amdgcn_mfma_f32_16x16x32_bf16(pf1, vf1, O[nt], 0, 0, 0);
    }

    if (nxt) {   // write prefetched chunk into the other buffer
      const int nb = buf ^ 1;
      *(uint4*)&Ks [nb][srow * KV_STRIDE + sseg]     = kr0;
      *(uint4*)&Ks [nb][srow * KV_STRIDE + sseg + 8] = kr1;
      *(uint4*)&VTs[nb][srow * KV_STRIDE + sseg]     = vr0;
      *(uint4*)&VTs[nb][srow * KV_STRIDE + sseg + 8] = vr1;
      if (tid < 64) Msk[nb][tid] = mreg ? -16.0f : -1e30f;
    }
    __syncthreads();
  }

  // deferred l reduction: per-lane partials -> cross-quad
  float ls = lacc;
  ls += __shfl_xor(ls, 16);
  ls += __shfl_xor(ls, 32);
  float linv = 1.0f / ls;
  float lO[4];
#pragma unroll
  for (int r = 0; r < 4; r++) lO[r] = __shfl(linv, quad*4 + r);
#pragma unroll
  for (int nt = 0; nt < 4; nt++)
#pragma unroll
    for (int r = 0; r < 4; r++) {
      size_t row = (size_t)(b * T_SEQ + q0 + quad*4 + r);
      ctx[row * D_MODEL + h * DH + nt*16 + lr] = (bf16)(O[nt][r] * lO[r]);
    }
}

// ---------------- kernel 4: per-tensor activation quant-dequant --------------
__global__ __launch_bounds__(256) void act_qdq(
    const float* __restrict__ pre, const unsigned int* __restrict__ amaxp,
    const int* __restrict__ flag, void* __restrict__ outv, int n)
{
  int i = (blockIdx.x * blockDim.x + threadIdx.x) * 4;
  if (i >= n) return;
  float s = fmaxf(__uint_as_float(*amaxp) / 127.0f, 1e-8f);
  float4 v = *(const float4*)(pre + i);
  float o[4] = {v.x, v.y, v.z, v.w};
#pragma unroll
  for (int r = 0; r < 4; r++) {
    float q = rintf(o[r] / s);
    q = fminf(fmaxf(q, -127.f), 127.f);
    o[r] = q * s;
  }
  if (*flag) {
    *(float4*)((float*)outv + i) = make_float4(o[0], o[1], o[2], o[3]);
  } else {
    __align__(8) bf16 ob[4] = {(bf16)o[0], (bf16)o[1], (bf16)o[2], (bf16)o[3]};
    *(uint2*)((bf16*)outv + i) = *(uint2*)ob;
  }
}

// ---------------- launch -----------------------------------------------------
extern "C" void kernel_launch(void* const* d_in, const int* in_sizes, int n_in,
                              void* d_out, int out_size, void* d_ws, size_t ws_size,
                              hipStream_t stream) {
  const void* x    = d_in[0];
  const int*  mask = (const int*)d_in[1];
  const void* Wq = d_in[2]; const void* bq = d_in[3];
  const void* Wk = d_in[4]; const void* bk = d_in[5];
  const void* Wv = d_in[6]; const void* bv = d_in[7];
  const void* Wo = d_in[8]; const void* bo = d_in[9];

  char* ws = (char*)d_ws;
  int*  flag  = (int*)(ws + 0);
  unsigned int* amax = (unsigned int*)(ws + 64);
  float* biasf = (float*)(ws + 1024);
  bf16* Wt  = (bf16*)(ws + 16384);                    // 2 MB (rows: Q,K,V,O)
  bf16* xb  = (bf16*)(ws + 4194304);                  // 8 MB
  bf16* Qm  = (bf16*)(ws + 12582912);                 // 8 MB (pre-scaled)
  bf16* Km  = (bf16*)(ws + 20971520);                 // 8 MB
  bf16* VT  = (bf16*)(ws + 29360128);                 // 8 MB: VT[ch][token]
  bf16* Cm  = (bf16*)(ws + 4194304);                  // overlays xb
  float* pre = (float*)(ws + 12582912);               // overlays Qm+Km

  hipMemsetAsync(amax, 0, 4, stream);
  detect_dtype<<<1, 64, 0, stream>>>((const unsigned short*)x, flag);
  convert_x<<<4096, 256, 0, stream>>>(x, flag, xb, M_ROWS * D_MODEL);
  convert_bias<<<1, 256, 0, stream>>>(bq, bk, bv, bo, flag, biasf);
  qdq_weights<<<512, 256, 0, stream>>>(Wq, Wk, Wv, Wo, flag, Wt);
  gemm_qkv<<<dim3(64, 12), 256, 0, stream>>>(xb, Wt, biasf, Qm, Km, VT);
  attn<<<dim3(64, 16), 256, 0, stream>>>(Qm, Km, VT, mask, Cm);
  gemm_o<<<dim3(128, 4), 256, 0, stream>>>(Cm, Wt + 3*262144, biasf + 1536, pre, amax);
  act_qdq<<<4096, 256, 0, stream>>>(pre, amax, flag, d_out, M_ROWS * D_MODEL);
}

// Round 7
// 301.267 us; speedup vs baseline: 1.7091x; 1.0230x over previous
//
#include <hip/hip_runtime.h>
#include <hip/hip_bf16.h>

typedef __bf16 bf16;
typedef __bf16 bf16x8 __attribute__((ext_vector_type(8)));
typedef __bf16 bf16x4v __attribute__((ext_vector_type(4)));
typedef float f32x4 __attribute__((ext_vector_type(4)));

#define D_MODEL 512
#define T_SEQ   4096
#define NH      8
#define DH      64
#define M_ROWS  8192   // B*T
#define QK_SCALE 0.18033688011112042f   // 0.125 * log2(e), folded into Q

// ---------------- kernel 0: dtype detector ----------------------------------
__global__ __launch_bounds__(64) void detect_dtype(const unsigned short* __restrict__ xr,
                                                   int* __restrict__ flag)
{
  int lane = threadIdx.x;
  int cnt = 0;
  for (int i = lane; i < 4096; i += 64) {
    unsigned short u = xr[i];
    int e = (u >> 7) & 0xFF;
    bool insane = (e >= 133) || (e > 0 && e <= 96) || (e == 0 && (u & 0x7F) != 0);
    cnt += insane ? 1 : 0;
  }
#pragma unroll
  for (int off = 32; off >= 1; off >>= 1) cnt += __shfl_xor(cnt, off);
  if (lane == 0) *flag = (cnt > 400) ? 1 : 0;   // 1 = inputs are fp32
}

// ---------------- kernel 0b: convert x to bf16 -------------------------------
__global__ __launch_bounds__(256) void convert_x(const void* __restrict__ xr,
                                                 const int* __restrict__ flag,
                                                 bf16* __restrict__ xb, int n)
{
  int i = (blockIdx.x * blockDim.x + threadIdx.x) * 4;
  if (i >= n) return;
  if (*flag) {
    float4 v = *(const float4*)((const float*)xr + i);
    __align__(8) bf16 o[4] = {(bf16)v.x, (bf16)v.y, (bf16)v.z, (bf16)v.w};
    *(uint2*)(xb + i) = *(uint2*)o;
  } else {
    *(uint2*)(xb + i) = *(const uint2*)((const bf16*)xr + i);
  }
}

// ---------------- kernel 0c: biases -> fp32, mask -> float shift -------------
__global__ __launch_bounds__(1024) void prep_aux(
    const void* b0, const void* b1, const void* b2, const void* b3,
    const int* __restrict__ mask,
    const int* __restrict__ flag, float* __restrict__ bf, float* __restrict__ mf)
{
  const void* ps[4] = {b0, b1, b2, b3};
  int fl = *flag;
  for (int t = threadIdx.x; t < 4 * D_MODEL; t += 1024) {
    int w = t >> 9, o = t & 511;
    bf[t] = fl ? ((const float*)ps[w])[o] : (float)((const bf16*)ps[w])[o];
  }
  for (int j = threadIdx.x; j < M_ROWS; j += 1024)
    mf[j] = mask[j] ? -16.0f : -1e30f;     // fixed-shift (exp2 domain) + mask
}

// ---------------- kernel 1: per-output-channel weight quant-dequant ----------
__global__ __launch_bounds__(256) void qdq_weights(
    const void* __restrict__ Wq, const void* __restrict__ Wk,
    const void* __restrict__ Wv, const void* __restrict__ Wo,
    const int* __restrict__ flag, bf16* __restrict__ out)
{
  int wave = threadIdx.x >> 6, lane = threadIdx.x & 63;
  int gid = blockIdx.x * 4 + wave;
  int w = gid >> 9, row = gid & 511;
  const void* W = (w == 0) ? Wq : (w == 1) ? Wk : (w == 2) ? Wv : Wo;
  int fl = *flag;
  float v[8]; float amax = 0.f;
#pragma unroll
  for (int i = 0; i < 8; i++) {
    int idx = row * D_MODEL + lane + 64 * i;
    v[i] = fl ? ((const float*)W)[idx] : (float)((const bf16*)W)[idx];
    amax = fmaxf(amax, fabsf(v[i]));
  }
#pragma unroll
  for (int off = 32; off >= 1; off >>= 1) amax = fmaxf(amax, __shfl_xor(amax, off));
  float s = fmaxf(amax / 127.0f, 1e-8f);
  bf16* dst = out + (size_t)gid * D_MODEL;
#pragma unroll
  for (int i = 0; i < 8; i++) {
    float q = rintf(v[i] / s);
    q = fminf(fmaxf(q, -127.f), 127.f);
    dst[lane + 64*i] = (bf16)(q * s);
  }
}

// ---------------- kernel 2a: fused QKV GEMM ----------------------------------
#define LDS_STRIDE 40
__global__ __launch_bounds__(256) void gemm_qkv(
    const bf16* __restrict__ A, const bf16* __restrict__ W,
    const float* __restrict__ bias,
    bf16* __restrict__ Qm, bf16* __restrict__ Km, bf16* __restrict__ VT)
{
  __shared__ __align__(16) bf16 As[128 * LDS_STRIDE];
  __shared__ __align__(16) bf16 Bs[128 * LDS_STRIDE];

  const int tid = threadIdx.x;
  const int wave = tid >> 6, lane = tid & 63;
  const int lr = lane & 15, quad = lane >> 4;
  const int wm = (wave >> 1) * 64, wn = (wave & 1) * 64;
  const int m0 = blockIdx.x * 128, n0 = blockIdx.y * 128;
  const int sec = blockIdx.y >> 2;   // 0=Q 1=K 2=V

  f32x4 acc[4][4];
#pragma unroll
  for (int i = 0; i < 4; i++)
#pragma unroll
    for (int j = 0; j < 4; j++) acc[i][j] = f32x4{0.f, 0.f, 0.f, 0.f};

  const int srow = tid >> 2;
  const int sseg = (tid & 3) * 8;

  for (int k0 = 0; k0 < D_MODEL; k0 += 32) {
#pragma unroll
    for (int i = 0; i < 2; i++) {
      int r = srow + i * 64;
      *(uint4*)&As[r * LDS_STRIDE + sseg] = *(const uint4*)(A + (size_t)(m0 + r) * D_MODEL + k0 + sseg);
      *(uint4*)&Bs[r * LDS_STRIDE + sseg] = *(const uint4*)(W + (size_t)(n0 + r) * D_MODEL + k0 + sseg);
    }
    __syncthreads();
    bf16x8 af[4], bfr[4];
#pragma unroll
    for (int mt = 0; mt < 4; mt++) af[mt]  = *(bf16x8*)&As[(wm + mt*16 + lr) * LDS_STRIDE + quad*8];
#pragma unroll
    for (int nt = 0; nt < 4; nt++) bfr[nt] = *(bf16x8*)&Bs[(wn + nt*16 + lr) * LDS_STRIDE + quad*8];
#pragma unroll
    for (int mt = 0; mt < 4; mt++)
#pragma unroll
      for (int nt = 0; nt < 4; nt++)
        acc[mt][nt] = __builtin_amdgcn_mfma_f32_16x16x32_bf16(af[mt], bfr[nt], acc[mt][nt], 0, 0, 0);
    __syncthreads();
  }

  const float scale = (sec == 0) ? QK_SCALE : 1.0f;
#pragma unroll
  for (int mt = 0; mt < 4; mt++) {
    int grow = m0 + wm + mt * 16 + quad * 4;
#pragma unroll
    for (int nt = 0; nt < 4; nt++) {
      int gcol = n0 + wn + nt * 16 + lr;
      float b = bias[gcol];
      if (sec == 2) {               // VT[ch][token], packed x4
        bf16x4v pk;
#pragma unroll
        for (int r = 0; r < 4; r++) pk[r] = (bf16)(acc[mt][nt][r] + b);
        *(bf16x4v*)(VT + (size_t)(gcol - 1024) * M_ROWS + grow) = pk;
      } else {
        bf16* dst = (sec == 0) ? Qm : Km;
        int c = gcol & 511;
#pragma unroll
        for (int r = 0; r < 4; r++)
          dst[(size_t)(grow + r) * D_MODEL + c] = (bf16)((acc[mt][nt][r] + b) * scale);
      }
    }
  }
}

// ---------------- kernel 2b: O-proj GEMM, 64x128, fp32 out + absmax ----------
__global__ __launch_bounds__(256) void gemm_o(
    const bf16* __restrict__ A, const bf16* __restrict__ W,
    const float* __restrict__ bias,
    float* __restrict__ Cf, unsigned int* __restrict__ amaxp)
{
  __shared__ __align__(16) bf16 As[64 * LDS_STRIDE];
  __shared__ __align__(16) bf16 Bs[128 * LDS_STRIDE];
  __shared__ float wred[4];

  const int tid = threadIdx.x;
  const int wave = tid >> 6, lane = tid & 63;
  const int lr = lane & 15, quad = lane >> 4;
  const int wm = (wave >> 1) * 32, wn = (wave & 1) * 64;
  const int m0 = blockIdx.x * 64, n0 = blockIdx.y * 128;

  f32x4 acc[2][4];
#pragma unroll
  for (int i = 0; i < 2; i++)
#pragma unroll
    for (int j = 0; j < 4; j++) acc[i][j] = f32x4{0.f, 0.f, 0.f, 0.f};

  const int srow = tid >> 2;
  const int sseg = (tid & 3) * 8;

  for (int k0 = 0; k0 < D_MODEL; k0 += 32) {
    *(uint4*)&As[srow * LDS_STRIDE + sseg] = *(const uint4*)(A + (size_t)(m0 + srow) * D_MODEL + k0 + sseg);
#pragma unroll
    for (int i = 0; i < 2; i++) {
      int r = srow + i * 64;
      *(uint4*)&Bs[r * LDS_STRIDE + sseg] = *(const uint4*)(W + (size_t)(n0 + r) * D_MODEL + k0 + sseg);
    }
    __syncthreads();
    bf16x8 af[2], bfr[4];
#pragma unroll
    for (int mt = 0; mt < 2; mt++) af[mt]  = *(bf16x8*)&As[(wm + mt*16 + lr) * LDS_STRIDE + quad*8];
#pragma unroll
    for (int nt = 0; nt < 4; nt++) bfr[nt] = *(bf16x8*)&Bs[(wn + nt*16 + lr) * LDS_STRIDE + quad*8];
#pragma unroll
    for (int mt = 0; mt < 2; mt++)
#pragma unroll
      for (int nt = 0; nt < 4; nt++)
        acc[mt][nt] = __builtin_amdgcn_mfma_f32_16x16x32_bf16(af[mt], bfr[nt], acc[mt][nt], 0, 0, 0);
    __syncthreads();
  }

  float lmax = 0.f;
#pragma unroll
  for (int mt = 0; mt < 2; mt++) {
    int grow = m0 + wm + mt * 16 + quad * 4;
#pragma unroll
    for (int nt = 0; nt < 4; nt++) {
      int gcol = n0 + wn + nt * 16 + lr;
      float b = bias[gcol];
#pragma unroll
      for (int r = 0; r < 4; r++) {
        float v = acc[mt][nt][r] + b;
        Cf[(size_t)(grow + r) * D_MODEL + gcol] = v;
        lmax = fmaxf(lmax, fabsf(v));
      }
    }
  }
#pragma unroll
  for (int off = 32; off >= 1; off >>= 1) lmax = fmaxf(lmax, __shfl_xor(lmax, off));
  if (lane == 0) wred[wave] = lmax;
  __syncthreads();
  if (tid == 0) {
    float m = fmaxf(fmaxf(wred[0], wred[1]), fmaxf(wred[2], wred[3]));
    atomicMax(amaxp, __float_as_uint(m));
  }
}

// ---------------- kernel 3: wave-autonomous flash attention ------------------
// 1024 blocks x 64 thr (1 wave). Wave owns 64 q-rows; NO __syncthreads.
// K A-frags / V B-frags / mask C-init loaded DIRECTLY from global (L2-resident
// via XCD swizzle: 2 (b,h) pairs per XCD -> 4MB working set per XCD L2).
// LDS only for the P (C-layout -> A-layout) roundtrip, same-wave ordering.
#define PB_STRIDE 72
__global__ __launch_bounds__(64, 1) void attn(
    const bf16* __restrict__ Q, const bf16* __restrict__ K, const bf16* __restrict__ VT,
    const float* __restrict__ maskf, bf16* __restrict__ ctx)
{
  __shared__ __align__(16) bf16 Pb[64 * PB_STRIDE];

  const int lane = threadIdx.x;
  const int lr = lane & 15, quad = lane >> 4;
  // XCD swizzle: linear%8 = XCD -> give each XCD 2 bh values
  const int i = blockIdx.x;
  const int bh = (i & 7) * 2 + ((i >> 3) & 1);
  const int qb = i >> 4;
  const int b = bh >> 3, h = bh & 7;
  const int q0 = qb * 64;

  // Q as B-frags: qf[qt][kh], B[k=dh][n=q=lr]
  bf16x8 qf[4][2];
#pragma unroll
  for (int qt = 0; qt < 4; qt++) {
    const bf16* rq = Q + (size_t)(b * T_SEQ + q0 + qt*16 + lr) * D_MODEL + h * DH;
    qf[qt][0] = *(const bf16x8*)(rq + quad * 8);
    qf[qt][1] = *(const bf16x8*)(rq + 32 + quad * 8);
  }

  f32x4 O[4][4];   // O[qt][nt]: C-layout row=quad*4+r (q), col=lr (dh)
#pragma unroll
  for (int a = 0; a < 4; a++)
#pragma unroll
    for (int c = 0; c < 4; c++) O[a][c] = f32x4{0.f, 0.f, 0.f, 0.f};
  float lacc[4] = {0.f, 0.f, 0.f, 0.f};

  const bf16* Kb = K  + (size_t)(b * T_SEQ) * D_MODEL + h * DH;   // K[token][512]
  const bf16* Vb = VT + (size_t)(h * DH) * M_ROWS + b * T_SEQ;    // VT[dh][8192]
  const float* mb = maskf + b * T_SEQ;

  // A-frag K: kr[kt][kh] = K[kb+kt*16+lr][dh = kh*32+quad*8 ..+8]
  // B-frag V: vr[nt][ks] = V[key = ks*32+quad*8 ..+8][dh = nt*16+lr]
  bf16x8 kr[4][2], vr[4][2];
  f32x4 mk[4];
#pragma unroll
  for (int kt = 0; kt < 4; kt++) {
    const bf16* rk = Kb + (size_t)(kt*16 + lr) * D_MODEL;
    kr[kt][0] = *(const bf16x8*)(rk + quad*8);
    kr[kt][1] = *(const bf16x8*)(rk + 32 + quad*8);
    mk[kt] = *(const f32x4*)(mb + kt*16 + quad*4);
  }
#pragma unroll
  for (int nt = 0; nt < 4; nt++) {
    const bf16* rv = Vb + (size_t)(nt*16 + lr) * M_ROWS;
    vr[nt][0] = *(const bf16x8*)(rv + quad*8);
    vr[nt][1] = *(const bf16x8*)(rv + 32 + quad*8);
  }

  for (int kb = 0; kb < T_SEQ; kb += 64) {
    const bool nxt = (kb + 64) < T_SEQ;

    // S^T = K.Q^T per (qt,kt); mask+shift as C-init; exp2 -> Pb
#pragma unroll
    for (int qt = 0; qt < 4; qt++) {
      f32x4 z[4];
#pragma unroll
      for (int kt = 0; kt < 4; kt++) {
        f32x4 t = mk[kt];
        t = __builtin_amdgcn_mfma_f32_16x16x32_bf16(kr[kt][0], qf[qt][0], t, 0, 0, 0);
        t = __builtin_amdgcn_mfma_f32_16x16x32_bf16(kr[kt][1], qf[qt][1], t, 0, 0, 0);
        z[kt] = t;
      }
      float la = lacc[qt];
#pragma unroll
      for (int kt = 0; kt < 4; kt++) {
        bf16x4v pk;
#pragma unroll
        for (int r = 0; r < 4; r++) {
          float p = exp2f(z[kt][r]);
          la += p;
          pk[r] = (bf16)p;
        }
        *(bf16x4v*)&Pb[(qt*16 + lr) * PB_STRIDE + kt*16 + quad*4] = pk;
      }
      lacc[qt] = la;
    }

    if (nxt) {  // kr & mk dead -> prefetch next chunk's K + mask
#pragma unroll
      for (int kt = 0; kt < 4; kt++) {
        const bf16* rk = Kb + (size_t)(kb + 64 + kt*16 + lr) * D_MODEL;
        kr[kt][0] = *(const bf16x8*)(rk + quad*8);
        kr[kt][1] = *(const bf16x8*)(rk + 32 + quad*8);
        mk[kt] = *(const f32x4*)(mb + kb + 64 + kt*16 + quad*4);
      }
    }

    // P back as A-frags (same-wave LDS, ordered)
    bf16x8 pf[4][2];
#pragma unroll
    for (int qt = 0; qt < 4; qt++) {
      pf[qt][0] = *(bf16x8*)&Pb[(qt*16 + lr) * PB_STRIDE + quad*8];
      pf[qt][1] = *(bf16x8*)&Pb[(qt*16 + lr) * PB_STRIDE + 32 + quad*8];
    }

    // PV accumulate
#pragma unroll
    for (int nt = 0; nt < 4; nt++)
#pragma unroll
      for (int qt = 0; qt < 4; qt++) {
        O[qt][nt] = __builtin_amdgcn_mfma_f32_16x16x32_bf16(pf[qt][0], vr[nt][0], O[qt][nt], 0, 0, 0);
        O[qt][nt] = __builtin_amdgcn_mfma_f32_16x16x32_bf16(pf[qt][1], vr[nt][1], O[qt][nt], 0, 0, 0);
      }

    if (nxt) {  // vr dead -> prefetch next chunk's V
#pragma unroll
      for (int nt = 0; nt < 4; nt++) {
        const bf16* rv = Vb + (size_t)(nt*16 + lr) * M_ROWS + kb + 64;
        vr[nt][0] = *(const bf16x8*)(rv + quad*8);
        vr[nt][1] = *(const bf16x8*)(rv + 32 + quad*8);
      }
    }
  }

  // epilogue: normalize + store
#pragma unroll
  for (int qt = 0; qt < 4; qt++) {
    float ls = lacc[qt];
    ls += __shfl_xor(ls, 16);
    ls += __shfl_xor(ls, 32);
    float linv = 1.0f / ls;
    float lO[4];
#pragma unroll
    for (int r = 0; r < 4; r++) lO[r] = __shfl(linv, quad*4 + r);
#pragma unroll
    for (int nt = 0; nt < 4; nt++)
#pragma unroll
      for (int r = 0; r < 4; r++) {
        size_t row = (size_t)(b * T_SEQ + q0 + qt*16 + quad*4 + r);
        ctx[row * D_MODEL + h * DH + nt*16 + lr] = (bf16)(O[qt][nt][r] * lO[r]);
      }
  }
}

// ---------------- kernel 4: per-tensor activation quant-dequant --------------
__global__ __launch_bounds__(256) void act_qdq(
    const float* __restrict__ pre, const unsigned int* __restrict__ amaxp,
    const int* __restrict__ flag, void* __restrict__ outv, int n)
{
  int i = (blockIdx.x * blockDim.x + threadIdx.x) * 4;
  if (i >= n) return;
  float s = fmaxf(__uint_as_float(*amaxp) / 127.0f, 1e-8f);
  float4 v = *(const float4*)(pre + i);
  float o[4] = {v.x, v.y, v.z, v.w};
#pragma unroll
  for (int r = 0; r < 4; r++) {
    float q = rintf(o[r] / s);
    q = fminf(fmaxf(q, -127.f), 127.f);
    o[r] = q * s;
  }
  if (*flag) {
    *(float4*)((float*)outv + i) = make_float4(o[0], o[1], o[2], o[3]);
  } else {
    __align__(8) bf16 ob[4] = {(bf16)o[0], (bf16)o[1], (bf16)o[2], (bf16)o[3]};
    *(uint2*)((bf16*)outv + i) = *(uint2*)ob;
  }
}

// ---------------- launch -----------------------------------------------------
extern "C" void kernel_launch(void* const* d_in, const int* in_sizes, int n_in,
                              void* d_out, int out_size, void* d_ws, size_t ws_size,
                              hipStream_t stream) {
  const void* x    = d_in[0];
  const int*  mask = (const int*)d_in[1];
  const void* Wq = d_in[2]; const void* bq = d_in[3];
  const void* Wk = d_in[4]; const void* bk = d_in[5];
  const void* Wv = d_in[6]; const void* bv = d_in[7];
  const void* Wo = d_in[8]; const void* bo = d_in[9];

  char* ws = (char*)d_ws;
  int*  flag  = (int*)(ws + 0);
  unsigned int* amax = (unsigned int*)(ws + 64);
  float* biasf = (float*)(ws + 1024);                 // 8 KB
  float* maskf = (float*)(ws + 16384);                // 32 KB
  bf16* Wt  = (bf16*)(ws + 65536);                    // 2 MB
  bf16* xb  = (bf16*)(ws + 4194304);                  // 8 MB
  bf16* Qm  = (bf16*)(ws + 12582912);                 // 8 MB (pre-scaled)
  bf16* Km  = (bf16*)(ws + 20971520);                 // 8 MB
  bf16* VT  = (bf16*)(ws + 29360128);                 // 8 MB: VT[ch][token]
  bf16* Cm  = (bf16*)(ws + 4194304);                  // overlays xb
  float* pre = (float*)(ws + 12582912);               // overlays Qm+Km

  hipMemsetAsync(amax, 0, 4, stream);
  detect_dtype<<<1, 64, 0, stream>>>((const unsigned short*)x, flag);
  convert_x<<<4096, 256, 0, stream>>>(x, flag, xb, M_ROWS * D_MODEL);
  prep_aux<<<1, 1024, 0, stream>>>(bq, bk, bv, bo, mask, flag, biasf, maskf);
  qdq_weights<<<512, 256, 0, stream>>>(Wq, Wk, Wv, Wo, flag, Wt);
  gemm_qkv<<<dim3(64, 12), 256, 0, stream>>>(xb, Wt, biasf, Qm, Km, VT);
  attn<<<1024, 64, 0, stream>>>(Qm, Km, VT, maskf, Cm);
  gemm_o<<<dim3(128, 4), 256, 0, stream>>>(Cm, Wt + 3*262144, biasf + 1536, pre, amax);
  act_qdq<<<4096, 256, 0, stream>>>(pre, amax, flag, d_out, M_ROWS * D_MODEL);
}